// Round 10
// baseline (217.983 us; speedup 1.0000x reference)
//
#include <hip/hip_runtime.h>

typedef _Float16 h2 __attribute__((ext_vector_type(2)));

// ---- DPP wave-64 inclusive sum (VALU pipe): full sum lands in lane 63 ----
template <int CTRL>
__device__ __forceinline__ float dpp_stage(float v) {
    int x = __builtin_amdgcn_update_dpp(0, __float_as_int(v), CTRL, 0xf, 0xf, true);
    return v + __int_as_float(x);
}
__device__ __forceinline__ float wave_sum(float v) {
    v = dpp_stage<0x111>(v);  // row_shr:1
    v = dpp_stage<0x112>(v);  // row_shr:2
    v = dpp_stage<0x114>(v);  // row_shr:4
    v = dpp_stage<0x118>(v);  // row_shr:8
    v = dpp_stage<0x142>(v);  // row_bcast:15
    v = dpp_stage<0x143>(v);  // row_bcast:31
    return v;                 // lane 63 holds the full sum
}
__device__ __forceinline__ float bcast63(float v) {
    return __int_as_float(__builtin_amdgcn_readlane(__float_as_int(v), 63));
}
__device__ __forceinline__ h2 mid2(h2 lo, h2 hi) {
    // (lo.y, hi.x) in one whole-register op: v_alignbit_b32
    int r = __builtin_amdgcn_alignbit(__builtin_bit_cast(int, hi),
                                      __builtin_bit_cast(int, lo), 16);
    return __builtin_bit_cast(h2, r);
}
__device__ __forceinline__ h2 pkrtz(float a, float b) {
    return __builtin_bit_cast(h2, __builtin_amdgcn_cvt_pkrtz(a, b));
}

// Compiler-level memory fence (emits nothing): pins LDS load/store program
// order so the single-wave no-barrier scheme is safe against LICM/reordering
// (round-1 stale-neighbor bug; fences validated PASS in rounds 2-3). The
// hardware DS pipe is in-order per wave, so program order alone suffices.
#define MEMFENCE() asm volatile("" ::: "memory")

// 27 taps x 4 z-pairs as NAMED h2 SSA values (w0a..w26d): with
// __launch_bounds__(64,2) the allocator may use up to 256 VGPRs, so these
// 108 values stay register-resident (rounds 1-3/8-9 spilled them because the
// default occupancy target capped VGPRs at 52-92).
#define R27(M) M(0) M(1) M(2) M(3) M(4) M(5) M(6) M(7) M(8) M(9) M(10) M(11) \
    M(12) M(13) M(14) M(15) M(16) M(17) M(18) M(19) M(20) M(21) M(22) M(23)  \
    M(24) M(25) M(26)

#define LOADW(T)                                                               \
    h2 w##T##a, w##T##b, w##T##c, w##T##d;                                     \
    {                                                                          \
        const float* wp = W + ((size_t)(T) << 18) + ofs;                       \
        float4 fa = *(const float4*)(wp);                                      \
        float4 fb = *(const float4*)(wp + 4);                                  \
        w##T##a = pkrtz(fa.x, fa.y); w##T##b = pkrtz(fa.z, fa.w);              \
        w##T##c = pkrtz(fb.x, fb.y); w##T##d = pkrtz(fb.z, fb.w);              \
        sw0 += fa.x; sw1 += fa.y; sw2 += fa.z; sw3 += fa.w;                    \
        sw4 += fb.x; sw5 += fb.y; sw6 += fb.z; sw7 += fb.w;                    \
    }

// one window column at h2-offset O (= 5*(10*dx+dy)), taps T0,T1,T2 (literals):
// 5 LDS dword reads from ONE base VGPR via offset immediates, 4 alignbit,
// 12 v_pk_fma_f16 covering all 4 output z-pairs of this thread.
#define COLT(O, T0, T1, T2) {                                                  \
    h2 D0 = bp[(O) + 0], D1 = bp[(O) + 1], D2 = bp[(O) + 2],                   \
       D3 = bp[(O) + 3], D4 = bp[(O) + 4];                                     \
    h2 M0 = mid2(D0, D1), M1 = mid2(D1, D2), M2 = mid2(D2, D3),                \
       M3 = mid2(D3, D4);                                                      \
    dd0 = __builtin_elementwise_fma(D0, w##T0##a, dd0);                        \
    dd1 = __builtin_elementwise_fma(D1, w##T0##b, dd1);                        \
    dd2 = __builtin_elementwise_fma(D2, w##T0##c, dd2);                        \
    dd3 = __builtin_elementwise_fma(D3, w##T0##d, dd3);                        \
    dd0 = __builtin_elementwise_fma(M0, w##T1##a, dd0);                        \
    dd1 = __builtin_elementwise_fma(M1, w##T1##b, dd1);                        \
    dd2 = __builtin_elementwise_fma(M2, w##T1##c, dd2);                        \
    dd3 = __builtin_elementwise_fma(M3, w##T1##d, dd3);                        \
    dd0 = __builtin_elementwise_fma(D1, w##T2##a, dd0);                        \
    dd1 = __builtin_elementwise_fma(D2, w##T2##b, dd1);                        \
    dd2 = __builtin_elementwise_fma(D3, w##T2##c, dd2);                        \
    dd3 = __builtin_elementwise_fma(D4, w##T2##d, dd3); }

// normalized-dot correction + bias + silu + residual for one output
#define OUTK(CK, DDF, SWK, BK, RK) {                                           \
    float u = fmaf(fmaf(SWK, nmean, DDF), istd, BK);                           \
    CK += RK * (u * __builtin_amdgcn_rcpf(1.f + __expf(-u))); }

__global__ __launch_bounds__(64, 2)
void gridnet_kernel(const float* __restrict__ W,
                    const float* __restrict__ Bias,
                    const float* __restrict__ Rs,
                    const float* __restrict__ X,
                    float* __restrict__ Y,
                    int n_batch)
{
    // single buffer: 10x10 columns x 10 z-halves = 2 KB. One wave per block =>
    // LDS ops complete in program order; with the MEMFENCEs pinning compiler
    // order, no ping-pong and ZERO barriers are needed.
    __shared__ __align__(16) h2 buf[500];

    const int tid = threadIdx.x;    // 0..63, one wave
    const int lx  = tid >> 3;       // 0..7
    const int ly  = tid & 7;

    // natural block order (round 4: XCD swizzle costs 20% via lockstep)
    const int bid   = (int)blockIdx.x;
    const int r     = bid / n_batch;          // spatial block 0..511
    const int batch = bid - r * n_batch;
    const int gm0 = (r >> 6) << 3;
    const int gn0 = ((r >> 3) & 7) << 3;
    const int gk0 = (r & 7) << 3;

    const float* xb = X + ((size_t)batch << 18);

    // -------- stage: each lane packs 1-2 whole z-columns; stats on rounded --
    float s_all = 0.f, q_all = 0.f, s_int = 0.f, q_int = 0.f;
    #pragma unroll 1
    for (int c = tid; c < 100; c += 64) {
        int x = c / 10, y = c - (c / 10) * 10;   // padded coords 0..9
        int m = gm0 + x - 1, n = gn0 + y - 1;
        bool row_ok = ((unsigned)m < 64u) & ((unsigned)n < 64u);
        float4 fa = {0.f, 0.f, 0.f, 0.f}, fb = {0.f, 0.f, 0.f, 0.f};
        float vz0 = 0.f, vz9 = 0.f;
        if (row_ok) {
            const float* rp = xb + (m * 4096 + n * 64);
            fa = *(const float4*)(rp + gk0);          // z = 1..4
            fb = *(const float4*)(rp + gk0 + 4);      // z = 5..8
            if (gk0 > 0)  vz0 = rp[gk0 - 1];          // uniform branches
            if (gk0 < 56) vz9 = rp[gk0 + 8];
        }
        h2 d0 = pkrtz(vz0, fa.x), d1 = pkrtz(fa.y, fa.z), d2 = pkrtz(fa.w, fb.x),
           d3 = pkrtz(fb.y, fb.z), d4 = pkrtz(fb.w, vz9);
        buf[c * 5 + 0] = d0; buf[c * 5 + 1] = d1; buf[c * 5 + 2] = d2;
        buf[c * 5 + 3] = d3; buf[c * 5 + 4] = d4;
        // stats over the f16-rounded values the dot will see
        float t0 = (float)d0.x, t1 = (float)d0.y, t2 = (float)d1.x,
              t3 = (float)d1.y, t4 = (float)d2.x, t5 = (float)d2.y,
              t6 = (float)d3.x, t7 = (float)d3.y, t8 = (float)d4.x,
              t9 = (float)d4.y;
        float s8 = t1 + t2 + t3 + t4 + t5 + t6 + t7 + t8;
        float q8 = t1*t1 + t2*t2 + t3*t3 + t4*t4 + t5*t5 + t6*t6 + t7*t7 + t8*t8;
        s_all += s8 + t0 + t9;
        q_all += q8 + t0*t0 + t9*t9;
        bool inter = ((unsigned)(x - 1) < 8u) & ((unsigned)(y - 1) < 8u);
        if (inter) { s_int += s8; q_int += q8; }
    }
    MEMFENCE();   // staging writes stay above everything below

    // -------- per-thread params: 27 taps x 8 k as 108 named h2 registers ----
    const int gm = gm0 + lx, gn = gn0 + ly;
    const size_t ofs = ((size_t)gm << 12) + (gn << 6) + gk0;
    float sw0=0.f, sw1=0.f, sw2=0.f, sw3=0.f, sw4=0.f, sw5=0.f, sw6=0.f, sw7=0.f;
    R27(LOADW)
    float4 ba = *(const float4*)(Bias + ofs), bb = *(const float4*)(Bias + ofs + 4);
    float4 ra = *(const float4*)(Rs + ofs),   rb = *(const float4*)(Rs + ofs + 4);

    // -------- one-time block stats: DPP + readlane only (single wave) -------
    float S_all = bcast63(wave_sum(s_all));
    float Q_all = bcast63(wave_sum(q_all));
    float Si    = bcast63(wave_sum(s_int));
    float Qi    = bcast63(wave_sum(q_int));
    const float halo_s = S_all - Si;
    const float halo_q = Q_all - Qi;

    // -------- own column initial state (rounded values from LDS) ------------
    h2* bp = &buf[5 * (lx * 10 + ly)];     // window corner; own col = +55 dwords
    h2 e0 = bp[55], e1 = bp[56], e2 = bp[57], e3 = bp[58], e4 = bp[59];
    float z0f = (float)e0.x, z9f = (float)e4.y;       // frozen z-halo halves
    float c1 = (float)e0.y, c2 = (float)e1.x, c3 = (float)e1.y, c4 = (float)e2.x,
          c5 = (float)e2.y, c6 = (float)e3.x, c7 = (float)e3.y, c8 = (float)e4.x;

    const float inv_n = 1.0f / 1000.0f;

    #pragma unroll 1
    for (int it = 0; it < 8; ++it) {
        float mean  = (halo_s + Si) * inv_n;
        float qmean = (halo_q + Qi) * inv_n;
        float istd  = rsqrtf(qmean - mean * mean + 1e-5f);
        float nmean = -mean;

        h2 dd0 = { (_Float16)0.f, (_Float16)0.f };
        h2 dd1 = dd0, dd2 = dd0, dd3 = dd0;
        COLT(0,   0,  1,  2)
        COLT(5,   3,  4,  5)
        COLT(10,  6,  7,  8)
        COLT(50,  9, 10, 11)
        COLT(55, 12, 13, 14)
        COLT(60, 15, 16, 17)
        COLT(100, 18, 19, 20)
        COLT(105, 21, 22, 23)
        COLT(110, 24, 25, 26)

        MEMFENCE();  // all 27 column reads issue before the stores below

        OUTK(c1, (float)dd0.x, sw0, ba.x, ra.x)
        OUTK(c2, (float)dd0.y, sw1, ba.y, ra.y)
        OUTK(c3, (float)dd1.x, sw2, ba.z, ra.z)
        OUTK(c4, (float)dd1.y, sw3, ba.w, ra.w)
        OUTK(c5, (float)dd2.x, sw4, bb.x, rb.x)
        OUTK(c6, (float)dd2.y, sw5, bb.y, rb.y)
        OUTK(c7, (float)dd3.x, sw6, bb.z, rb.z)
        OUTK(c8, (float)dd3.y, sw7, bb.w, rb.w)

        // write back own column (frozen z-halo halves preserved)
        e0 = pkrtz(z0f, c1); e1 = pkrtz(c2, c3); e2 = pkrtz(c4, c5);
        e3 = pkrtz(c6, c7); e4 = pkrtz(c8, z9f);
        bp[55] = e0; bp[56] = e1; bp[57] = e2; bp[58] = e3; bp[59] = e4;

        MEMFENCE();  // stores stay above next iteration's reads (no LICM hoist)

        // interior sums for next iteration's stats (DPP chain overlaps writes)
        float sp = ((c1 + c2) + (c3 + c4)) + ((c5 + c6) + (c7 + c8));
        float qp = ((c1*c1 + c2*c2) + (c3*c3 + c4*c4)) +
                   ((c5*c5 + c6*c6) + (c7*c7 + c8*c8));
        Si = bcast63(wave_sum(sp));
        Qi = bcast63(wave_sum(qp));
    }

    float* yp = Y + ((size_t)batch << 18) + ofs;
    *(float4*)(yp)     = make_float4(c1, c2, c3, c4);
    *(float4*)(yp + 4) = make_float4(c5, c6, c7, c8);
}

extern "C" void kernel_launch(void* const* d_in, const int* in_sizes, int n_in,
                              void* d_out, int out_size, void* d_ws, size_t ws_size,
                              hipStream_t stream) {
    const float* W = (const float*)d_in[0];   // (27,64,64,64)
    const float* B = (const float*)d_in[1];   // (64,64,64)
    const float* R = (const float*)d_in[2];   // (64,64,64)
    const float* X = (const float*)d_in[3];   // (16,64,64,64)
    float* Y = (float*)d_out;

    int n_batch = in_sizes[3] >> 18;          // 64^3 per sample
    dim3 grid(512 * n_batch), block(64);
    hipLaunchKernelGGL(gridnet_kernel, grid, block, 0, stream, W, B, R, X, Y, n_batch);
}

// Round 11
// 170.065 us; speedup vs baseline: 1.2818x; 1.2818x over previous
//
#include <hip/hip_runtime.h>

typedef _Float16 h2 __attribute__((ext_vector_type(2)));

#define CSTR 7     // column stride in DWORDS (odd -> bank spread)
#define COLH 14    // halves per column (= 2*CSTR): z0 halo, z1..8, z9 halo, 4 pad

// ---- DPP wave-64 sum (VALU pipe): full sum lands in lane 63 ----
template <int CTRL>
__device__ __forceinline__ float dpp_stage(float v) {
    int x = __builtin_amdgcn_update_dpp(0, __float_as_int(v), CTRL, 0xf, 0xf, true);
    return v + __int_as_float(x);
}
__device__ __forceinline__ float wave_sum(float v) {
    v = dpp_stage<0x111>(v);  // row_shr:1
    v = dpp_stage<0x112>(v);  // row_shr:2
    v = dpp_stage<0x114>(v);  // row_shr:4
    v = dpp_stage<0x118>(v);  // row_shr:8
    v = dpp_stage<0x142>(v);  // row_bcast:15
    v = dpp_stage<0x143>(v);  // row_bcast:31
    return v;
}

#define RFL(x) __int_as_float(__builtin_amdgcn_readfirstlane(__float_as_int(x)))

__device__ __forceinline__ h2 mid2(h2 lo, h2 hi) {
    int r = __builtin_amdgcn_alignbit(__builtin_bit_cast(int, hi),
                                      __builtin_bit_cast(int, lo), 16);
    return __builtin_bit_cast(h2, r);
}
__device__ __forceinline__ h2 pkrtz(float a, float b) {
    return __builtin_bit_cast(h2, __builtin_amdgcn_cvt_pkrtz(a, b));
}

// ---- 27 taps x 4 z PINNED IN AGPRs ----
// Every prior round's weights were silently REMATERIALIZED from global memory
// each iteration (r10 proof: launch_bounds(64,2) allowed 256 VGPR, allocator
// still chose 88, FETCH inflated 127->196MB). An asm accvgpr_write output has
// no memory provenance -> LLVM cannot remat it; weights become truly resident
// at zero memory traffic. Read back per use via v_accvgpr_read (plain VALU).
#define R27(M) M(0) M(1) M(2) M(3) M(4) M(5) M(6) M(7) M(8) M(9) M(10) M(11) \
    M(12) M(13) M(14) M(15) M(16) M(17) M(18) M(19) M(20) M(21) M(22) M(23)  \
    M(24) M(25) M(26)

#define LOADW(T)                                                               \
    int aw##T##p, aw##T##q;                                                    \
    {                                                                          \
        const float* wp = W + ((size_t)(T) << 18) + ofs;                       \
        float4 f = *(const float4*)(wp);                                       \
        h2 hp = pkrtz(f.x, f.y), hq = pkrtz(f.z, f.w);                         \
        asm volatile("v_accvgpr_write_b32 %0, %1"                              \
                     : "=a"(aw##T##p) : "v"(__builtin_bit_cast(int, hp)));     \
        asm volatile("v_accvgpr_write_b32 %0, %1"                              \
                     : "=a"(aw##T##q) : "v"(__builtin_bit_cast(int, hq)));     \
        sw0 += f.x; sw1 += f.y; sw2 += f.z; sw3 += f.w;                        \
    }

#define AGRD(DST, SRC)                                                         \
    int _i##DST; asm volatile("v_accvgpr_read_b32 %0, %1"                      \
                              : "=v"(_i##DST) : "a"(SRC));                     \
    h2 DST = __builtin_bit_cast(h2, _i##DST);

// one window column at dword offset O, taps T0..T2, BOTH batches fused:
// 6 AGPR reads (each weight once), 6 LDS dword reads, 4 alignbit,
// 12 v_pk_fma_f16 -> 8 outputs (4z x 2 batches). Low liveness.
#define COL2(O, T0, T1, T2) {                                                  \
    AGRD(wp0, aw##T0##p) AGRD(wq0, aw##T0##q)                                  \
    AGRD(wp1, aw##T1##p) AGRD(wq1, aw##T1##q)                                  \
    AGRD(wp2, aw##T2##p) AGRD(wq2, aw##T2##q)                                  \
    h2 a0 = bpA[(O)], a1 = bpA[(O) + 1], a2 = bpA[(O) + 2];                    \
    h2 am0 = mid2(a0, a1), am1 = mid2(a1, a2);                                 \
    ddA0 = __builtin_elementwise_fma(a0,  wp0, ddA0);                          \
    ddA1 = __builtin_elementwise_fma(a1,  wq0, ddA1);                          \
    ddA0 = __builtin_elementwise_fma(am0, wp1, ddA0);                          \
    ddA1 = __builtin_elementwise_fma(am1, wq1, ddA1);                          \
    ddA0 = __builtin_elementwise_fma(a1,  wp2, ddA0);                          \
    ddA1 = __builtin_elementwise_fma(a2,  wq2, ddA1);                          \
    h2 b0 = bpB[(O)], b1 = bpB[(O) + 1], b2 = bpB[(O) + 2];                    \
    h2 bm0 = mid2(b0, b1), bm1 = mid2(b1, b2);                                 \
    ddB0 = __builtin_elementwise_fma(b0,  wp0, ddB0);                          \
    ddB1 = __builtin_elementwise_fma(b1,  wq0, ddB1);                          \
    ddB0 = __builtin_elementwise_fma(bm0, wp1, ddB0);                          \
    ddB1 = __builtin_elementwise_fma(bm1, wq1, ddB1);                          \
    ddB0 = __builtin_elementwise_fma(b1,  wp2, ddB0);                          \
    ddB1 = __builtin_elementwise_fma(b2,  wq2, ddB1); }

#define SILU(U) ((U) * __builtin_amdgcn_rcpf(1.f + __expf(-(U))))

// norm + bias + silu + residual + LDS writeback for one batch's 4 outputs
#define EPI4(DD0, DD1, SI, QI, HS, HQ, C0, C1, C2, C3, DSTB) {                 \
    float mean = (HS + SI) * inv_n;                                            \
    float istd = rsqrtf((HQ + QI) * inv_n - mean * mean + 1e-5f);              \
    float u0 = ((float)DD0.x - mean * sw0) * istd + bf.x;                      \
    float u1 = ((float)DD0.y - mean * sw1) * istd + bf.y;                      \
    float u2 = ((float)DD1.x - mean * sw2) * istd + bf.z;                      \
    float u3 = ((float)DD1.y - mean * sw3) * istd + bf.w;                      \
    C0 += rf.x * SILU(u0);                                                     \
    C1 += rf.y * SILU(u1);                                                     \
    C2 += rf.z * SILU(u2);                                                     \
    C3 += rf.w * SILU(u3);                                                     \
    DSTB[ipc] = (_Float16)C0;                                                  \
    *(h2*)&DSTB[ipc + 1] = pkrtz(C1, C2);                                      \
    DSTB[ipc + 3] = (_Float16)C3;  }

// one inner iteration for the thread's TWO batches (A,B), column-fused;
// ONE 2-wave barrier.
#define ITERP(BPA_, DSTA, BPB_, DSTB, RED) {                                   \
    const h2* bpA = BPA_;                                                      \
    const h2* bpB = BPB_;                                                      \
    h2 ddA0 = { (_Float16)0.f, (_Float16)0.f };                                \
    h2 ddA1 = ddA0, ddB0 = ddA0, ddB1 = ddA0;                                  \
    COL2(0,    0,  1,  2)                                                      \
    COL2(7,    3,  4,  5)                                                      \
    COL2(14,   6,  7,  8)                                                      \
    COL2(70,   9, 10, 11)                                                      \
    COL2(77,  12, 13, 14)                                                      \
    COL2(84,  15, 16, 17)                                                      \
    COL2(140, 18, 19, 20)                                                      \
    COL2(147, 21, 22, 23)                                                      \
    COL2(154, 24, 25, 26)                                                      \
    EPI4(ddA0, ddA1, SiA, QiA, halo_sA, halo_qA, cA0, cA1, cA2, cA3, DSTA)     \
    EPI4(ddB0, ddB1, SiB, QiB, halo_sB, halo_qB, cB0, cB1, cB2, cB3, DSTB)     \
    float spA = wave_sum((cA0 + cA1) + (cA2 + cA3));                           \
    float qpA = wave_sum((cA0 * cA0 + cA1 * cA1) + (cA2 * cA2 + cA3 * cA3));   \
    float spB = wave_sum((cB0 + cB1) + (cB2 + cB3));                           \
    float qpB = wave_sum((cB0 * cB0 + cB1 * cB1) + (cB2 * cB2 + cB3 * cB3));   \
    if (lane == 63) { RED[0][wave] = make_float2(spA, qpA);                    \
                      RED[1][wave] = make_float2(spB, qpB); }                  \
    __syncthreads();                                                           \
    SiA = RFL(RED[0][0].x + RED[0][1].x);                                      \
    QiA = RFL(RED[0][0].y + RED[0][1].y);                                      \
    SiB = RFL(RED[1][0].x + RED[1][1].x);                                      \
    QiB = RFL(RED[1][0].y + RED[1][1].y); }

__global__ __launch_bounds__(128, 3)
void gridnet_kernel(const float* __restrict__ W,
                    const float* __restrict__ Bias,
                    const float* __restrict__ Rs,
                    const float* __restrict__ X,
                    float* __restrict__ Y,
                    int n_batch)
{
    // 2 batches/wg: [batch][pingpong], 2.8 KB each = 11.2 KB
    __shared__ __align__(16) _Float16 buf[2][2][100 * COLH];
    __shared__ float4 red4[2][2];          // [batch][wave] one-time stats
    __shared__ float2 redP[2][2][2];       // [pingpong][batch][wave]

    const int tid = threadIdx.x;           // 0..127, 2 waves
    const int h    = tid & 1;
    const int ly   = (tid >> 1) & 7;
    const int lx   = (tid >> 4) & 7;
    const int wave = tid >> 6;             // 0,1
    const int lane = tid & 63;

    // NO XCD swizzle (round 4: cuts FETCH 5x but costs 20% via lockstep).
    const int np    = n_batch >> 1;        // batch PAIRS per tile
    const int bid   = blockIdx.x;
    const int r     = bid / np;            // spatial block 0..511
    const int pb    = bid - r * np;
    const int batch0 = 2 * pb;             // this wg: batches batch0, batch0+1
    const int gm0 = (r >> 6) << 3;
    const int gn0 = ((r >> 3) & 7) << 3;
    const int gk0 = (r & 7) << 3;

    const float* xb = X + ((size_t)batch0 << 18);

    // -------- stage 10x10x10 (zero halo) for 2 batches; stats on rounded ----
    float sA_all = 0.f, qA_all = 0.f, sA_int = 0.f, qA_int = 0.f;
    float sB_all = 0.f, qB_all = 0.f, sB_int = 0.f, qB_int = 0.f;
    for (int i = tid; i < 1000; i += 128) {
        int ix = i / 100;
        int rem = i - ix * 100;
        int iy = rem / 10;
        int iz = rem - iy * 10;
        int m = gm0 + ix - 1, n = gn0 + iy - 1, k = gk0 + iz - 1;
        float vA = 0.f, vB = 0.f;
        if ((unsigned)m < 64u && (unsigned)n < 64u && (unsigned)k < 64u) {
            const float* p = xb + (m << 12) + (n << 6) + k;
            vA = p[0];
            vB = p[1 << 18];
        }
        _Float16 hA = (_Float16)vA, hB = (_Float16)vB;
        int a = (ix * 10 + iy) * COLH + iz;
        buf[0][0][a] = hA; buf[0][1][a] = hA;   // frozen halo in both pingpongs
        buf[1][0][a] = hB; buf[1][1][a] = hB;
        float fA = (float)hA, fB = (float)hB;
        sA_all += fA; qA_all += fA * fA;
        sB_all += fB; qB_all += fB * fB;
        bool interior = ((unsigned)(ix - 1) < 8u) & ((unsigned)(iy - 1) < 8u) &
                        ((unsigned)(iz - 1) < 8u);
        if (interior) { sA_int += fA; qA_int += fA * fA;
                        sB_int += fB; qB_int += fB * fB; }
    }

    // one-time reduction for both batches (8 independent DPP chains)
    {
        float a0 = wave_sum(sA_all), a1 = wave_sum(qA_all);
        float a2 = wave_sum(sA_int), a3 = wave_sum(qA_int);
        float b0 = wave_sum(sB_all), b1 = wave_sum(qB_all);
        float b2 = wave_sum(sB_int), b3 = wave_sum(qB_int);
        if (lane == 63) {
            red4[0][wave] = make_float4(a0, a1, a2, a3);
            red4[1][wave] = make_float4(b0, b1, b2, b3);
        }
    }

    // -------- per-thread params: 27 taps x 4 z pinned into 54 AGPRs ---------
    const int gm = gm0 + lx, gn = gn0 + ly;
    const size_t ofs = ((size_t)gm << 12) + (gn << 6) + gk0 + 4 * h;
    float sw0 = 0.f, sw1 = 0.f, sw2 = 0.f, sw3 = 0.f;
    R27(LOADW)
    const float4 bf = *(const float4*)(Bias + ofs);
    const float4 rf = *(const float4*)(Rs + ofs);

    __syncthreads();   // staging + red4 visible (2 waves)

    // gather both batches' stats
    float SA = 0.f, QA = 0.f, SiA = 0.f, QiA = 0.f;
    float SB = 0.f, QB = 0.f, SiB = 0.f, QiB = 0.f;
    #pragma unroll
    for (int wv = 0; wv < 2; ++wv) {
        float4 tA = red4[0][wv];
        float4 tB = red4[1][wv];
        SA += tA.x; QA += tA.y; SiA += tA.z; QiA += tA.w;
        SB += tB.x; QB += tB.y; SiB += tB.z; QiB += tB.w;
    }
    const float halo_sA = RFL(SA - SiA), halo_qA = RFL(QA - QiA);
    const float halo_sB = RFL(SB - SiB), halo_qB = RFL(QB - QiB);
    SiA = RFL(SiA); QiA = RFL(QiA);
    SiB = RFL(SiB); QiB = RFL(QiB);

    // -------- loop-invariant geometry ---------------------------------------
    const int bpD = (lx * 10 + ly) * CSTR + 2 * h;     // window-corner dword
    const h2* const bpA0 = (const h2*)buf[0][0] + bpD;
    const h2* const bpA1 = (const h2*)buf[0][1] + bpD;
    const h2* const bpB0 = (const h2*)buf[1][0] + bpD;
    const h2* const bpB1 = (const h2*)buf[1][1] + bpD;
    _Float16* const wrA0 = buf[0][0];
    _Float16* const wrA1 = buf[0][1];
    _Float16* const wrB0 = buf[1][0];
    _Float16* const wrB1 = buf[1][1];
    const int ipc = ((lx + 1) * 10 + (ly + 1)) * COLH + 4 * h + 1;
    float cA0 = (float)wrA0[ipc],     cA1 = (float)wrA0[ipc + 1];
    float cA2 = (float)wrA0[ipc + 2], cA3 = (float)wrA0[ipc + 3];
    float cB0 = (float)wrB0[ipc],     cB1 = (float)wrB0[ipc + 1];
    float cB2 = (float)wrB0[ipc + 2], cB3 = (float)wrB0[ipc + 3];

    const float inv_n = 1.0f / 1000.0f;

    // 8 iterations = 4 ping-pong pairs; one 2-wave barrier per iteration
    #pragma unroll 1
    for (int it = 0; it < 4; ++it) {
        ITERP(bpA0, wrA1, bpB0, wrB1, redP[0])
        ITERP(bpA1, wrA0, bpB1, wrB0, redP[1])
    }

    float* yp = Y + ((size_t)batch0 << 18) + ofs;
    *(float4*)yp = make_float4(cA0, cA1, cA2, cA3);
    *(float4*)(yp + (1 << 18)) = make_float4(cB0, cB1, cB2, cB3);
}

extern "C" void kernel_launch(void* const* d_in, const int* in_sizes, int n_in,
                              void* d_out, int out_size, void* d_ws, size_t ws_size,
                              hipStream_t stream) {
    const float* W = (const float*)d_in[0];   // (27,64,64,64)
    const float* B = (const float*)d_in[1];   // (64,64,64)
    const float* R = (const float*)d_in[2];   // (64,64,64)
    const float* X = (const float*)d_in[3];   // (16,64,64,64)
    float* Y = (float*)d_out;

    int n_batch = in_sizes[3] >> 18;          // 64^3 per sample (16, even)
    dim3 grid(512 * (n_batch >> 1)), block(128);
    hipLaunchKernelGGL(gridnet_kernel, grid, block, 0, stream, W, B, R, X, Y, n_batch);
}

// Round 12
// 143.821 us; speedup vs baseline: 1.5157x; 1.1825x over previous
//
#include <hip/hip_runtime.h>

typedef _Float16 h2 __attribute__((ext_vector_type(2)));
typedef _Float16 h8 __attribute__((ext_vector_type(8)));

#define WSTRIDE 108   // dwords per position in weight LDS (27 taps x 4 dwords).
                      // stride 108: lane L's b128 hits banks {12L..12L+3 mod 32}
                      // -> 8 lanes per 4-bank group -> conflict-free b128.

// ---- DPP wave-64 sum (VALU pipe): full sum lands in lane 63 ----
template <int CTRL>
__device__ __forceinline__ float dpp_stage(float v) {
    int x = __builtin_amdgcn_update_dpp(0, __float_as_int(v), CTRL, 0xf, 0xf, true);
    return v + __int_as_float(x);
}
__device__ __forceinline__ float wave_sum(float v) {
    v = dpp_stage<0x111>(v);  // row_shr:1
    v = dpp_stage<0x112>(v);  // row_shr:2
    v = dpp_stage<0x114>(v);  // row_shr:4
    v = dpp_stage<0x118>(v);  // row_shr:8
    v = dpp_stage<0x142>(v);  // row_bcast:15
    v = dpp_stage<0x143>(v);  // row_bcast:31
    return v;
}
__device__ __forceinline__ float bcast63(float v) {
    return __int_as_float(__builtin_amdgcn_readlane(__float_as_int(v), 63));
}
__device__ __forceinline__ h2 mid2(h2 lo, h2 hi) {
    int r = __builtin_amdgcn_alignbit(__builtin_bit_cast(int, hi),
                                      __builtin_bit_cast(int, lo), 16);
    return __builtin_bit_cast(h2, r);
}
__device__ __forceinline__ h2 pkrtz(float a, float b) {
    return __builtin_bit_cast(h2, __builtin_amdgcn_cvt_pkrtz(a, b));
}

// Compiler-level memory fence (emits nothing): pins LDS op program order.
// (a) single-wave read/write discipline on the private data buffer
//     (round-1 stale-neighbor bug; validated PASS r2/r3/r10);
// (b) forbids LICM-hoisting the loop-invariant LDS weight loads (which would
//     create 108 live VGPRs and re-trigger the spill disaster).
#define MEMFENCE() asm volatile("" ::: "memory")

// h2 slice k (elements 2k,2k+1) of an h8 — register-select, no instructions
#define SL(W, K) __builtin_shufflevector(W, W, 2*(K), 2*(K)+1)

// one window column at data-dword offset O, taps T..T+2 (weights from LDS):
// 3 ds_read_b128 (weights) + 5 LDS dword data reads + 4 alignbit +
// 36 v_pk_fma_f16 -> all 8 z outputs of this thread.
#define COLT(O, T) {                                                           \
    h8 WA = wp8[(T)];                                                          \
    h8 WB = wp8[(T) + 1];                                                      \
    h8 WC = wp8[(T) + 2];                                                      \
    h2 D0 = bp[(O) + 0], D1 = bp[(O) + 1], D2 = bp[(O) + 2],                   \
       D3 = bp[(O) + 3], D4 = bp[(O) + 4];                                     \
    h2 M0 = mid2(D0, D1), M1 = mid2(D1, D2), M2 = mid2(D2, D3),                \
       M3 = mid2(D3, D4);                                                      \
    dd0 = __builtin_elementwise_fma(D0, SL(WA, 0), dd0);                       \
    dd1 = __builtin_elementwise_fma(D1, SL(WA, 1), dd1);                       \
    dd2 = __builtin_elementwise_fma(D2, SL(WA, 2), dd2);                       \
    dd3 = __builtin_elementwise_fma(D3, SL(WA, 3), dd3);                       \
    dd0 = __builtin_elementwise_fma(M0, SL(WB, 0), dd0);                       \
    dd1 = __builtin_elementwise_fma(M1, SL(WB, 1), dd1);                       \
    dd2 = __builtin_elementwise_fma(M2, SL(WB, 2), dd2);                       \
    dd3 = __builtin_elementwise_fma(M3, SL(WB, 3), dd3);                       \
    dd0 = __builtin_elementwise_fma(D1, SL(WC, 0), dd0);                       \
    dd1 = __builtin_elementwise_fma(D2, SL(WC, 1), dd1);                       \
    dd2 = __builtin_elementwise_fma(D3, SL(WC, 2), dd2);                       \
    dd3 = __builtin_elementwise_fma(D4, SL(WC, 3), dd3); }

// normalized-dot correction + bias + silu + residual for one output
#define OUTK(CK, DDF, SWK, BK, RK) {                                           \
    float u = fmaf(fmaf(SWK, nmean, DDF), istd, BK);                           \
    CK += RK * (u * __builtin_amdgcn_rcpf(1.f + __expf(-u))); }

__global__ __launch_bounds__(256)
void gridnet_kernel(const float* __restrict__ W,
                    const float* __restrict__ Bias,
                    const float* __restrict__ Rs,
                    const float* __restrict__ X,
                    float* __restrict__ Y,
                    int n_batch)
{
    // weights: 64 positions x 27 taps x 8 f16 z-values, SHARED by all 4 waves
    __shared__ __align__(16) int wlds[64 * WSTRIDE];    // 27.6 KB
    // data: one private 10x10x10 f16 block per wave (batch); r10 layout:
    // column (x,y) at dword 5*(x*10+y), 5 h2 = z0..z9
    __shared__ __align__(16) h2 dbuf[4][500];           // 4 x 2 KB

    const int tid  = threadIdx.x;      // 256 threads = 4 independent waves
    const int wave = tid >> 6;
    const int lane = tid & 63;
    const int lx   = lane >> 3;        // 0..7
    const int ly   = lane & 7;

    // wave = one batch of the tile; 4 batches/wg share the weight LDS.
    const int nq    = n_batch >> 2;
    const int bid   = (int)blockIdx.x;
    const int r     = bid / nq;                 // spatial block 0..511
    const int qb    = bid - r * nq;
    const int batch = 4 * qb + wave;
    const int gm0 = (r >> 6) << 3;
    const int gn0 = ((r >> 3) & 7) << 3;
    const int gk0 = (r & 7) << 3;

    const float* xb = X + ((size_t)batch << 18);
    h2* const my = dbuf[wave];

    // -------- data staging (per wave, own batch); stats on rounded ----------
    float s_all = 0.f, q_all = 0.f, s_int = 0.f, q_int = 0.f;
    #pragma unroll 1
    for (int c = lane; c < 100; c += 64) {
        int x = c / 10, y = c - (c / 10) * 10;   // padded coords 0..9
        int m = gm0 + x - 1, n = gn0 + y - 1;
        bool row_ok = ((unsigned)m < 64u) & ((unsigned)n < 64u);
        float4 fa = {0.f, 0.f, 0.f, 0.f}, fb = {0.f, 0.f, 0.f, 0.f};
        float vz0 = 0.f, vz9 = 0.f;
        if (row_ok) {
            const float* rp = xb + (m * 4096 + n * 64);
            fa = *(const float4*)(rp + gk0);          // z = 1..4
            fb = *(const float4*)(rp + gk0 + 4);      // z = 5..8
            if (gk0 > 0)  vz0 = rp[gk0 - 1];          // uniform branches
            if (gk0 < 56) vz9 = rp[gk0 + 8];
        }
        h2 d0 = pkrtz(vz0, fa.x), d1 = pkrtz(fa.y, fa.z), d2 = pkrtz(fa.w, fb.x),
           d3 = pkrtz(fb.y, fb.z), d4 = pkrtz(fb.w, vz9);
        my[c * 5 + 0] = d0; my[c * 5 + 1] = d1; my[c * 5 + 2] = d2;
        my[c * 5 + 3] = d3; my[c * 5 + 4] = d4;
        float t0 = (float)d0.x, t1 = (float)d0.y, t2 = (float)d1.x,
              t3 = (float)d1.y, t4 = (float)d2.x, t5 = (float)d2.y,
              t6 = (float)d3.x, t7 = (float)d3.y, t8 = (float)d4.x,
              t9 = (float)d4.y;
        float s8 = t1 + t2 + t3 + t4 + t5 + t6 + t7 + t8;
        float q8 = t1*t1 + t2*t2 + t3*t3 + t4*t4 + t5*t5 + t6*t6 + t7*t7 + t8*t8;
        s_all += s8 + t0 + t9;
        q_all += q8 + t0*t0 + t9*t9;
        bool inter = ((unsigned)(x - 1) < 8u) & ((unsigned)(y - 1) < 8u);
        if (inter) { s_int += s8; q_int += q8; }
    }

    // -------- cooperative weight staging: 27 taps x 64 positions ------------
    #pragma unroll 1
    for (int j = tid; j < 1728; j += 256) {
        int tap = j >> 6;                   // 0..26
        int pos = j & 63;
        int plx = pos >> 3, ply = pos & 7;
        const float* wp = W + ((size_t)tap << 18)
                        + (((size_t)(gm0 + plx)) << 12) + ((gn0 + ply) << 6) + gk0;
        float4 fa = *(const float4*)(wp);
        float4 fb = *(const float4*)(wp + 4);
        int4 v = { __builtin_bit_cast(int, pkrtz(fa.x, fa.y)),
                   __builtin_bit_cast(int, pkrtz(fa.z, fa.w)),
                   __builtin_bit_cast(int, pkrtz(fb.x, fb.y)),
                   __builtin_bit_cast(int, pkrtz(fb.z, fb.w)) };
        *(int4*)&wlds[pos * WSTRIDE + tap * 4] = v;     // aligned ds_write_b128
    }

    // -------- per-wave block stats: DPP + readlane only ---------------------
    float S_all = bcast63(wave_sum(s_all));
    float Q_all = bcast63(wave_sum(q_all));
    float Si    = bcast63(wave_sum(s_int));
    float Qi    = bcast63(wave_sum(q_int));
    const float halo_s = S_all - Si;
    const float halo_q = Q_all - Qi;

    __syncthreads();   // the ONLY barrier: weights visible to all 4 waves

    // -------- per-thread loop-invariant state -------------------------------
    const h8* const wp8 = (const h8*)&wlds[lane * WSTRIDE];   // own weights
    h2* const bp = &my[5 * (lx * 10 + ly)];   // window corner; own col = +55

    // sw sums over the ROUNDED weights (what the dot sees)
    float sw0=0.f, sw1=0.f, sw2=0.f, sw3=0.f, sw4=0.f, sw5=0.f, sw6=0.f, sw7=0.f;
    #pragma unroll
    for (int t = 0; t < 27; ++t) {
        h8 w = wp8[t];
        sw0 += (float)w[0]; sw1 += (float)w[1]; sw2 += (float)w[2];
        sw3 += (float)w[3]; sw4 += (float)w[4]; sw5 += (float)w[5];
        sw6 += (float)w[6]; sw7 += (float)w[7];
    }

    const size_t ofs = (((size_t)(gm0 + lx)) << 12) + ((gn0 + ly) << 6) + gk0;
    float4 ba = *(const float4*)(Bias + ofs), bb = *(const float4*)(Bias + ofs + 4);
    float4 ra = *(const float4*)(Rs + ofs),   rb = *(const float4*)(Rs + ofs + 4);

    // own column initial state (rounded values from LDS)
    h2 e0 = bp[55], e1 = bp[56], e2 = bp[57], e3 = bp[58], e4 = bp[59];
    float z0f = (float)e0.x, z9f = (float)e4.y;       // frozen z-halo halves
    float c1 = (float)e0.y, c2 = (float)e1.x, c3 = (float)e1.y, c4 = (float)e2.x,
          c5 = (float)e2.y, c6 = (float)e3.x, c7 = (float)e3.y, c8 = (float)e4.x;

    const float inv_n = 1.0f / 1000.0f;

    // 8 iterations, ZERO barriers (single-wave discipline + fences)
    #pragma unroll 1
    for (int it = 0; it < 8; ++it) {
        float mean  = (halo_s + Si) * inv_n;
        float qmean = (halo_q + Qi) * inv_n;
        float istd  = rsqrtf(qmean - mean * mean + 1e-5f);
        float nmean = -mean;

        h2 dd0 = { (_Float16)0.f, (_Float16)0.f };
        h2 dd1 = dd0, dd2 = dd0, dd3 = dd0;
        COLT(0,    0)
        COLT(5,    3)
        COLT(10,   6)
        COLT(50,   9)
        COLT(55,  12)
        COLT(60,  15)
        COLT(100, 18)
        COLT(105, 21)
        COLT(110, 24)

        MEMFENCE();  // all column reads issue before the stores below

        OUTK(c1, (float)dd0.x, sw0, ba.x, ra.x)
        OUTK(c2, (float)dd0.y, sw1, ba.y, ra.y)
        OUTK(c3, (float)dd1.x, sw2, ba.z, ra.z)
        OUTK(c4, (float)dd1.y, sw3, ba.w, ra.w)
        OUTK(c5, (float)dd2.x, sw4, bb.x, rb.x)
        OUTK(c6, (float)dd2.y, sw5, bb.y, rb.y)
        OUTK(c7, (float)dd3.x, sw6, bb.z, rb.z)
        OUTK(c8, (float)dd3.y, sw7, bb.w, rb.w)

        if (it != 7) {   // last iteration: no writeback, no stats
            e0 = pkrtz(z0f, c1); e1 = pkrtz(c2, c3); e2 = pkrtz(c4, c5);
            e3 = pkrtz(c6, c7); e4 = pkrtz(c8, z9f);
            bp[55] = e0; bp[56] = e1; bp[57] = e2; bp[58] = e3; bp[59] = e4;

            MEMFENCE();  // stores stay above next iteration's reads

            float sp = ((c1 + c2) + (c3 + c4)) + ((c5 + c6) + (c7 + c8));
            float qp = ((c1*c1 + c2*c2) + (c3*c3 + c4*c4)) +
                       ((c5*c5 + c6*c6) + (c7*c7 + c8*c8));
            Si = bcast63(wave_sum(sp));
            Qi = bcast63(wave_sum(qp));
        }
    }

    float* yp = Y + ((size_t)batch << 18) + ofs;
    *(float4*)(yp)     = make_float4(c1, c2, c3, c4);
    *(float4*)(yp + 4) = make_float4(c5, c6, c7, c8);
}

extern "C" void kernel_launch(void* const* d_in, const int* in_sizes, int n_in,
                              void* d_out, int out_size, void* d_ws, size_t ws_size,
                              hipStream_t stream) {
    const float* W = (const float*)d_in[0];   // (27,64,64,64)
    const float* B = (const float*)d_in[1];   // (64,64,64)
    const float* R = (const float*)d_in[2];   // (64,64,64)
    const float* X = (const float*)d_in[3];   // (16,64,64,64)
    float* Y = (float*)d_out;

    int n_batch = in_sizes[3] >> 18;          // 64^3 per sample (16, div by 4)
    dim3 grid(512 * (n_batch >> 2)), block(256);
    hipLaunchKernelGGL(gridnet_kernel, grid, block, 0, stream, W, B, R, X, Y, n_batch);
}